// Round 14
// baseline (119.951 us; speedup 1.0000x reference)
//
#include <hip/hip_runtime.h>

#define NROWS 32768
#define NE    1024
#define ED    64
#define PAIRS 8                 // 8 pair-iterations x (64+64) codes
#define RPW   8                 // rows per wave
#define RPB   32                // rows per block

typedef float4 f4;

// ---------------------------------------------------------------------------
// Prep: per-code ||e||^2 with numpy pairwise-8 op order (exact f32 replication)
// ---------------------------------------------------------------------------
__global__ void vq_prep(const float* __restrict__ cb, float* __restrict__ ssq)
{
    int j = blockIdx.x * blockDim.x + threadIdx.x;   // 0..1023
    const f4* crow = (const f4*)(cb + (size_t)j * ED);
    f4 v[16];
#pragma unroll
    for (int i = 0; i < 16; ++i) v[i] = crow[i];
    {
#pragma clang fp contract(off)
        float r0 = v[0].x*v[0].x, r1 = v[0].y*v[0].y;
        float r2 = v[0].z*v[0].z, r3 = v[0].w*v[0].w;
        float r4 = v[1].x*v[1].x, r5 = v[1].y*v[1].y;
        float r6 = v[1].z*v[1].z, r7 = v[1].w*v[1].w;
#pragma unroll
        for (int q = 2; q < 16; q += 2) {
            r0 += v[q].x*v[q].x;     r1 += v[q].y*v[q].y;
            r2 += v[q].z*v[q].z;     r3 += v[q].w*v[q].w;
            r4 += v[q+1].x*v[q+1].x; r5 += v[q+1].y*v[q+1].y;
            r6 += v[q+1].z*v[q+1].z; r7 += v[q+1].w*v[q+1].w;
        }
        ssq[j] = ((r0+r1)+(r2+r3)) + ((r4+r5)+(r6+r7));
    }
}

// ---------------------------------------------------------------------------
// Main: RPW=8 (LDS-read traffic halved vs r13) AND 8192 waves (2x r7 TLP)
// via in-block code-split with PAIRED staging:
//  - 1024 blocks x 512 thr = 8 waves; wave (rg = w&3, half = w>>2) owns
//    8 rows x 512 codes. Chunk pair (p, p+8) staged together in LDS
//    [slot][k4][code] f4 (32 KB) -> both halves compute EVERY period.
//  - per k4: 1 ds_read_b128 (e, 0-conflict r10 pattern) + 8 wave-uniform
//    s_load_dwordx4 (z) + 32 FMAs. Staging = b128 writes (cheap).
// Numerics identical per (row,code) to passing r3/r6/r7/r13: cn/ssq numpy
// pairwise-8; dot ascending-k single-acc fmaf; d = fl(fl(cn+ssq)-2*acc);
// first-index argmin (ascending codes per lane, lex (d,idx) across lanes
// and across halves).
// ---------------------------------------------------------------------------
__global__ __launch_bounds__(512)
void vq_main(const float* __restrict__ z, const float* __restrict__ cb,
             const float* __restrict__ ssq, float* __restrict__ out,
             float* __restrict__ partials)
{
    __shared__ __align__(16) f4 eL4[2 * 16 * 64];    // 32 KB [slot][k4][code]
    __shared__ float cvsh[8][RPW];
    __shared__ int   cish[8][RPW];
    __shared__ int   idxsh[RPB];
    __shared__ float wsum[8];

    const int tid  = threadIdx.x;
    const int lane = tid & 63;
    const int w    = tid >> 6;                               // wave 0..7
    const int w_u  = __builtin_amdgcn_readfirstlane(w);      // scalar wave id
    const int half = w_u >> 2;                               // code half 0/1
    const int rg   = w_u & 3;                                // row group 0..3
    const int rowbase = blockIdx.x * RPB;

    const float* zw = z + (size_t)(rowbase + rg * RPW) * ED; // scalar base

    // ---- row norms for this wave's 8 rows, numpy pairwise-8 ----
    float cn[RPW];
    {
        const int rl = lane >> 3;            // row within wave's 8
        const int jj = lane & 7;             // accumulator index
        const float* zr = zw + (size_t)rl * ED;
        float a;
        {
#pragma clang fp contract(off)
            a = 0.f;
#pragma unroll
            for (int i = 0; i < 8; ++i) { float v = zr[8*i + jj]; a += v*v; }
        }
        a += __shfl_xor(a, 1);
        a += __shfl_xor(a, 2);
        a += __shfl_xor(a, 4);
#pragma unroll
        for (int r = 0; r < RPW; ++r) cn[r] = __shfl(a, r * 8);
    }

    float bestv[RPW];
    int   besti[RPW];
#pragma unroll
    for (int r = 0; r < RPW; ++r) { bestv[r] = INFINITY; besti[r] = 0; }

    for (int p = 0; p < PAIRS; ++p) {
        __syncthreads();   // previous pair's readers done
        // ---- stage pair (p, p+8): slot s = tid>>8, quarter h, code c ----
        {
            const int s = tid >> 8;           // slot 0/1
            const int h = (tid >> 6) & 3;     // dim quarter
            const int c = tid & 63;           // code within chunk
            const f4* crow = (const f4*)(cb + (size_t)((p + 8*s) * 64 + c) * ED
                                         + h * 16);
#pragma unroll
            for (int i = 0; i < 4; ++i)
                eL4[(size_t)(s * 16 + 4*h + i) * 64 + c] = crow[i];
        }
        __syncthreads();

        const int jlane = (p + 8 * half) * 64 + lane;   // this lane's code
        const float sq = ssq[jlane];                    // coalesced, L2-hot

        float acc[RPW];
#pragma unroll
        for (int r = 0; r < RPW; ++r) acc[r] = 0.f;

        const f4* eb = eL4 + (size_t)(half * 16) * 64;  // scalar slot base

#pragma unroll 4
        for (int k4 = 0; k4 < 16; ++k4) {
            f4 e  = eb[k4 * 64 + lane];                 // ds_read_b128
            f4 z0 = *(const f4*)(zw + 0*ED + 4*k4);     // s_load_dwordx4
            f4 z1 = *(const f4*)(zw + 1*ED + 4*k4);
            f4 z2 = *(const f4*)(zw + 2*ED + 4*k4);
            f4 z3 = *(const f4*)(zw + 3*ED + 4*k4);
            f4 z4 = *(const f4*)(zw + 4*ED + 4*k4);
            f4 z5 = *(const f4*)(zw + 5*ED + 4*k4);
            f4 z6 = *(const f4*)(zw + 6*ED + 4*k4);
            f4 z7 = *(const f4*)(zw + 7*ED + 4*k4);
#define ROWFMA(r, zz)                                 \
            acc[r] = fmaf(e.x, zz.x, acc[r]);         \
            acc[r] = fmaf(e.y, zz.y, acc[r]);         \
            acc[r] = fmaf(e.z, zz.z, acc[r]);         \
            acc[r] = fmaf(e.w, zz.w, acc[r]);
            ROWFMA(0, z0) ROWFMA(1, z1) ROWFMA(2, z2) ROWFMA(3, z3)
            ROWFMA(4, z4) ROWFMA(5, z5) ROWFMA(6, z6) ROWFMA(7, z7)
#undef ROWFMA
        }

        {
#pragma clang fp contract(off)
#pragma unroll
            for (int r = 0; r < RPW; ++r) {
                float t1 = cn[r] + sq;
                float d  = t1 - 2.0f * acc[r];          // 2*acc exact
                if (d < bestv[r]) { bestv[r] = d; besti[r] = jlane; }
            }
        }
    }

    // ---- cross-lane lexicographic (val, idx) argmin per row ----
#pragma unroll
    for (int r = 0; r < RPW; ++r) {
        float v = bestv[r];
        int   i = besti[r];
#pragma unroll
        for (int m = 1; m < 64; m <<= 1) {
            float ov = __shfl_xor(v, m);
            int   oi = __shfl_xor(i, m);
            if (ov < v || (ov == v && oi < i)) { v = ov; i = oi; }
        }
        if (lane == 0) { cvsh[w][r] = v; cish[w][r] = i; }
    }
    __syncthreads();

    // ---- combine the two halves per row (lex) + idx store ----
    if (tid < RPB) {
        const int rgg = tid >> 3;            // row group
        const int rr  = tid & 7;             // row within group
        float v0 = cvsh[rgg][rr];     int i0 = cish[rgg][rr];      // half 0
        float v1 = cvsh[rgg + 4][rr]; int i1 = cish[rgg + 4][rr];  // half 1
        int ii = (v1 < v0 || (v1 == v0 && i1 < i0)) ? i1 : i0;
        ii &= (NE - 1);                      // defensive no-op
        idxsh[tid] = ii;
        out[(size_t)NROWS * ED + rowbase + tid] = (float)ii;
    }
    __syncthreads();

    // ---- epilogue: thread -> (row = tid>>4, f4-col = tid&15) ----
    const int erow = tid >> 4;
    const int q4   = tid & 15;
    const int gi   = idxsh[erow];
    f4 e  = *(const f4*)(cb + (size_t)gi * ED + q4 * 4);
    f4 zz = *(const f4*)(z + (size_t)(rowbase + erow) * ED + q4 * 4);
    float lp;
    f4 o;
    {
#pragma clang fp contract(off)
        float d0 = e.x - zz.x; o.x = zz.x + d0;
        float d1 = e.y - zz.y; o.y = zz.y + d1;
        float d2 = e.z - zz.z; o.z = zz.z + d2;
        float d3 = e.w - zz.w; o.w = zz.w + d3;
        lp = ((d0*d0 + d1*d1) + (d2*d2 + d3*d3));
    }
    *(f4*)(out + (size_t)(rowbase + erow) * ED + q4 * 4) = o;

    // ---- deterministic loss partial ----
#pragma unroll
    for (int m = 1; m < 64; m <<= 1) lp += __shfl_xor(lp, m);
    if (lane == 0) wsum[w] = lp;
    __syncthreads();
    if (tid == 0)
        partials[blockIdx.x] = (((wsum[0]+wsum[1]) + (wsum[2]+wsum[3]))
                              + ((wsum[4]+wsum[5]) + (wsum[6]+wsum[7])));
}

// ---------------------------------------------------------------------------
// Finalize: deterministic tree-sum of 1024 partials -> loss scalar (f32)
// ---------------------------------------------------------------------------
__global__ void vq_finalize(const float* __restrict__ partials,
                            float* __restrict__ out)
{
    __shared__ float red[256];
    int t = threadIdx.x;
    float s = (partials[t] + partials[t + 256]) + (partials[t + 512] + partials[t + 768]);
    red[t] = s;
    __syncthreads();
    for (int m = 128; m > 0; m >>= 1) {
        if (t < m) red[t] += red[t + m];
        __syncthreads();
    }
    if (t == 0) {
        float mean = red[0] / (float)((size_t)NROWS * ED);
        out[(size_t)NROWS * ED + NROWS] = mean + 0.25f * mean;  // (1+BETA)*mean
    }
}

extern "C" void kernel_launch(void* const* d_in, const int* in_sizes, int n_in,
                              void* d_out, int out_size, void* d_ws, size_t ws_size,
                              hipStream_t stream)
{
    (void)in_sizes; (void)n_in; (void)out_size; (void)ws_size;
    const float* z  = (const float*)d_in[0];
    const float* cb = (const float*)d_in[1];
    float* out = (float*)d_out;
    float* ssq      = (float*)d_ws;          // 1024 f32
    float* partials = ssq + NE;              // 1024 f32

    vq_prep<<<4, 256, 0, stream>>>(cb, ssq);
    vq_main<<<1024, 512, 0, stream>>>(z, cb, ssq, out, partials);
    vq_finalize<<<1, 256, 0, stream>>>(partials, out);
}